// Round 12
// baseline (5647.473 us; speedup 1.0000x reference)
//
#include <hip/hip_runtime.h>

// DualEncoderLSTMDense: dual peephole-LSTM encoders (shared weights) + M-projection + tiny MLP.
// B=256, L=128, E=256, H=512, VOCAB=90000, NUM_NEG=4, forget_bias=2.0.
//
// Round 12: attack h-exchange MALL THROUGHPUT (R11 falsified latency). R8 duplicated each
// row-group's 128KB h slab across 32 hid-blocks = 32MB/step through the MALL (~1.3TB/s
// achieved = suspected ceiling). This round: block = 64 rows x 32 hid (512 thr, 8 waves),
// grid 128, -> 16 blocks/row-group -> 16MB/step. Unlike R10 (which streamed W and blew the
// 4MB/XCD L2 budget, FETCH 122MB->3.5GB), the ENTIRE h-part W_hi (128 W-rows x 512K x 2B
// = 128KB) sits in dynamic LDS (mechanism proven in R11). Streamed union/XCD = 16 x 256KB
// = 4MB = L2 budget. Product order identical -> bit-identical output (absmax 1.953e-3).

typedef unsigned short u16;
typedef unsigned long long u64;
typedef __attribute__((ext_vector_type(8))) short    s16x8;   // 8 bf16 = one MFMA A/B fragment
typedef __attribute__((ext_vector_type(4))) float    f32x4;
typedef __attribute__((ext_vector_type(4))) unsigned u32x4;

#define MFMA(a, b, c) __builtin_amdgcn_mfma_f32_16x16x32_bf16((a), (b), (c), 0, 0, 0)

__device__ __forceinline__ u16 f2bf(float f) {   // RNE float -> bf16
    union { float f; unsigned u; } v; v.f = f;
    unsigned r = v.u + 0x7FFFu + ((v.u >> 16) & 1u);
    return (u16)(r >> 16);
}
__device__ __forceinline__ float bf2f(u16 h) {
    union { unsigned u; float f; } v; v.u = ((unsigned)h) << 16;
    return v.f;
}
__device__ __forceinline__ float sigm(float x) { return 1.0f / (1.0f + expf(-x)); }

// ---- transpose fp32 [R][C] -> bf16 hi/lo planes [C][R] (R,C multiples of 32) ----
__global__ __launch_bounds__(256) void transpose_split(const float* __restrict__ src,
        u16* __restrict__ dhi, u16* __restrict__ dlo, int R, int C)
{
    __shared__ float tile[32][33];
    const int bx = blockIdx.x * 32;   // src col base
    const int by = blockIdx.y * 32;   // src row base
    for (int i = threadIdx.y; i < 32; i += 8)
        tile[i][threadIdx.x] = src[(size_t)(by + i) * C + bx + threadIdx.x];
    __syncthreads();
    for (int i = threadIdx.y; i < 32; i += 8) {
        float v = tile[threadIdx.x][i];
        u16 hi = f2bf(v);
        size_t o = (size_t)(bx + i) * R + by + threadIdx.x;
        dhi[o] = hi;
        dlo[o] = f2bf(v - bf2f(hi));
    }
}

// ---- zero h0 packed plane + barrier counters ----
__global__ __launch_bounds__(256) void zero_state(unsigned* __restrict__ h0p,
        unsigned* __restrict__ ctr)
{
    const int i = blockIdx.x * 256 + threadIdx.x;   // grid 1024*256 = 262144
    h0p[i] = 0;
    if (i < 8) ctr[i * 32] = 0;
}

// ---- persistent LSTM: all 128 steps, both encoders (512 batch rows) ----
// 128 blocks x 512 threads: rowTile = bid&7 (64 rows), hidTile = bid>>3 (32 hid cols).
// Wave w (0..7): row-sub = w>>1, hid-sub = w&1. Dynamic LDS 128KB = full h-part W_hi.
__global__ __launch_bounds__(512, 1) void lstm_persist(
        const float* __restrict__ emb, const int* __restrict__ qtok, const int* __restrict__ rtok,
        const int* __restrict__ qlen, const int* __restrict__ rlen,
        const u16* __restrict__ Wt_hi, const u16* __restrict__ Wt_lo,   // [2048][768]
        const float* __restrict__ bias, const float* __restrict__ wi,
        const float* __restrict__ wf, const float* __restrict__ wo,
        unsigned* __restrict__ h0p, unsigned* __restrict__ h1p,         // packed h planes
        unsigned* __restrict__ ctr)
{
    extern __shared__ char smem[];
    u16* whi_h = (u16*)smem;   // 128 KiB: 128 W-rows [4g*32c] x K 256..767, XOR-swizzled

    const int tid = threadIdx.x, lane = tid & 63, w = tid >> 6;
    const int bid = blockIdx.x;
    const int rowTile = bid & 7, hidTile = bid >> 3;
    const int row0 = rowTile * 64 + (w >> 1) * 16;
    const int hid0 = hidTile * 32 + (w & 1) * 16;
    const int frow = lane & 15, kgrp = lane >> 4;
    const int sw = (frow & 7) << 4;                // LDS XOR swizzle for this lane

    // ---- stage h-part W_hi into LDS (once): 128 W-rows x 64 chunks of 16B ----
    for (int i = tid; i < 8192; i += 512) {
        const int gc = i >> 6, c16 = i & 63;       // LDS W-row, 16B chunk within K-slice
        const int g = gc >> 5, cc = gc & 31;
        const s16x8 v = *(const s16x8*)(Wt_hi + (size_t)(g * 512 + hidTile * 32 + cc) * 768 + 256 + c16 * 8);
        *(s16x8*)((char*)whi_h + ((gc * 1024 + c16 * 16) ^ ((gc & 7) << 4))) = v;
    }

    // ---- per-thread constants ----
    const int   ohid = hid0 + frow;
    const float bi  = bias[ohid];
    const float bj  = bias[512 + ohid];
    const float bff = bias[1024 + ohid];
    const float bo  = bias[1536 + ohid];
    const float wiv = wi[ohid], wfv = wf[ohid], wov = wo[ohid];
    const int   arow = row0 + frow;                                 // A-fragment row
    const int*  tokp = (arow < 256) ? (qtok + arow * 128) : (rtok + (arow - 256) * 128);
    const u16*  whi_base[4];
    const u16*  wlo_base[4];
    #pragma unroll
    for (int g = 0; g < 4; ++g) {
        whi_base[g] = Wt_hi + (size_t)(g * 512 + hid0 + frow) * 768;
        wlo_base[g] = Wt_lo + (size_t)(g * 512 + hid0 + frow) * 768;
    }
    // LDS W-row index for this lane's B-fragments, per gate
    int ldsrow[4];
    #pragma unroll
    for (int g = 0; g < 4; ++g)
        ldsrow[g] = g * 32 + (w & 1) * 16 + frow;

    int lenv[4];
    #pragma unroll
    for (int r = 0; r < 4; ++r) {
        const int rr = row0 + kgrp * 4 + r;
        lenv[r] = (rr < 256) ? qlen[rr] : rlen[rr - 256];
    }
    float c_reg[4] = {0, 0, 0, 0}, h_reg[4] = {0, 0, 0, 0};

    __syncthreads();

    unsigned* myctr = ctr + rowTile * 32;

    for (int t = 0; t < 128; ++t) {
        const unsigned* rd = (t & 1) ? h1p : h0p;
        unsigned*       wr = (t & 1) ? h0p : h1p;

        // ---- x-part FIRST (depends only on tokens; overlaps barrier stragglers) ----
        const int    tok  = tokp[t];
        const float* xrow = emb + (size_t)tok * 256 + kgrp * 8;
        f32x4 fv[16];
        #pragma unroll
        for (int i = 0; i < 16; ++i)
            fv[i] = *(const f32x4*)(xrow + (i >> 1) * 32 + (i & 1) * 4);

        f32x4 acc[4] = {{0,0,0,0},{0,0,0,0},{0,0,0,0},{0,0,0,0}};  // gates i,j,f,o

        // x-part, K 0..255: split fp32 gather into 2 planes; bh/bl streamed (L2); 3 products
        #pragma unroll
        for (int ks = 0; ks < 8; ++ks) {
            const f32x4 v0 = fv[2 * ks], v1 = fv[2 * ks + 1];
            const float vv[8] = {v0[0], v0[1], v0[2], v0[3], v1[0], v1[1], v1[2], v1[3]};
            s16x8 xh, xl;
            #pragma unroll
            for (int e = 0; e < 8; ++e) {
                const u16 hb = f2bf(vv[e]);
                xh[e] = (short)hb;
                xl[e] = (short)f2bf(vv[e] - bf2f(hb));
            }
            const int kk = ks * 32 + kgrp * 8;
            #pragma unroll
            for (int g = 0; g < 4; ++g) {
                const s16x8 bh = *(const s16x8*)(whi_base[g] + kk);
                const s16x8 bl = *(const s16x8*)(wlo_base[g] + kk);
                acc[g] = MFMA(xh, bh, acc[g]);
                acc[g] = MFMA(xl, bh, acc[g]);
                acc[g] = MFMA(xh, bl, acc[g]);
            }
        }

        // ---- wait: all 16 group blocks must have PUBLISHED h(t-1) ----
        if (tid == 0) {
            const unsigned target = 16u * (unsigned)t;
            int it = 0;
            for (;;) {
                const unsigned v = ((it & 7) == 7)
                    ? __hip_atomic_fetch_add(myctr, 0u, __ATOMIC_RELAXED, __HIP_MEMORY_SCOPE_AGENT)
                    : __hip_atomic_load(myctr, __ATOMIC_RELAXED, __HIP_MEMORY_SCOPE_AGENT);
                if (v >= target) break;
                ++it;
                __builtin_amdgcn_s_sleep(1);
            }
        }
        __syncthreads();

        const unsigned* hrd = rd + arow * 512 + kgrp * 8;

        // h-part, K 256..767: A JIT from MALL (sc1); bh from LDS; bl streamed (L2); 4 products
        #pragma unroll 2
        for (int ks = 0; ks < 16; ++ks) {
            const int kh = ks * 32;
            s16x8 ah, al;
            #pragma unroll
            for (int i = 0; i < 4; ++i) {
                const u64 v = __hip_atomic_load((const u64*)(hrd + kh + 2 * i),
                                                __ATOMIC_RELAXED, __HIP_MEMORY_SCOPE_AGENT);
                const unsigned w0 = (unsigned)v, w1 = (unsigned)(v >> 32);
                ah[2 * i]     = (short)(u16)w0;
                al[2 * i]     = (short)(u16)(w0 >> 16);
                ah[2 * i + 1] = (short)(u16)w1;
                al[2 * i + 1] = (short)(u16)(w1 >> 16);
            }
            #pragma unroll
            for (int g = 0; g < 4; ++g) {
                const s16x8 bh = *(const s16x8*)((const char*)whi_h + ((ldsrow[g] * 1024 + (kh + kgrp * 8) * 2) ^ sw));
                const s16x8 bl = *(const s16x8*)(wlo_base[g] + 256 + kh + kgrp * 8);
                acc[g] = MFMA(ah, bh, acc[g]);
                acc[g] = MFMA(al, bh, acc[g]);
                acc[g] = MFMA(ah, bl, acc[g]);
                acc[g] = MFMA(al, bl, acc[g]);
            }
        }

        // gates + peepholes + masking (state in registers); publish h packed via sc1 store
        #pragma unroll
        for (int r = 0; r < 4; ++r) {
            const float cold = c_reg[r];
            const float ig = sigm(acc[0][r] + bi + wiv * cold);
            const float jg = tanhf(acc[1][r] + bj);
            const float fg = sigm(acc[2][r] + bff + wfv * cold + 2.0f);
            const float cn = fg * cold + ig * jg;
            const float og = sigm(acc[3][r] + bo + wov * cn);
            const float hn = og * tanhf(cn);
            const bool upd = (t < lenv[r]);
            c_reg[r] = upd ? cn : c_reg[r];
            h_reg[r] = upd ? hn : h_reg[r];
            const int off = (row0 + kgrp * 4 + r) * 512 + ohid;
            const u16 hb = f2bf(h_reg[r]);
            const u16 lb = f2bf(h_reg[r] - bf2f(hb));
            __hip_atomic_store(wr + off, ((unsigned)lb << 16) | (unsigned)hb,
                               __ATOMIC_RELAXED, __HIP_MEMORY_SCOPE_AGENT);
        }

        // ---- publish: drain this wave's stores (vmcnt), block-converge, one relaxed add ----
        asm volatile("s_waitcnt vmcnt(0)" ::: "memory");
        __syncthreads();
        if (tid == 0)
            __hip_atomic_fetch_add(myctr, 1u, __ATOMIC_RELAXED, __HIP_MEMORY_SCOPE_AGENT);
    }
}

// ---- qt[256][512] = q_h @ M (MFMA, h from packed plane, M hi+lo, 4 products) ----
// grid (8,16), 4 waves 2x2
__global__ __launch_bounds__(256) void qt_kernel(
        const unsigned* __restrict__ hpk,
        const u16* __restrict__ Mt_hi, const u16* __restrict__ Mt_lo, float* __restrict__ qt)
{
    const int tid = threadIdx.x, lane = tid & 63, w = tid >> 6;
    const int wr = w >> 1, wc = w & 1;
    const int row0 = blockIdx.x * 32 + wr * 16;
    const int col0 = blockIdx.y * 32 + wc * 16;
    const int frow = lane & 15, kgrp = lane >> 4;
    f32x4 acc = {0, 0, 0, 0};
    const unsigned* ap = hpk + (row0 + frow) * 512 + kgrp * 8;
    const u16* bph = Mt_hi + (col0 + frow) * 512 + kgrp * 8;
    const u16* bpl = Mt_lo + (col0 + frow) * 512 + kgrp * 8;
    #pragma unroll 4
    for (int ks = 0; ks < 16; ++ks) {
        const u32x4 a0 = *(const u32x4*)(ap + ks * 32);
        const u32x4 a1 = *(const u32x4*)(ap + ks * 32 + 4);
        s16x8 ah, al;
        #pragma unroll
        for (int i = 0; i < 4; ++i) {
            ah[i]     = (short)(u16)a0[i];
            al[i]     = (short)(u16)(a0[i] >> 16);
            ah[4 + i] = (short)(u16)a1[i];
            al[4 + i] = (short)(u16)(a1[i] >> 16);
        }
        const s16x8 bh = *(const s16x8*)(bph + ks * 32);
        const s16x8 bl = *(const s16x8*)(bpl + ks * 32);
        acc = MFMA(ah, bh, acc);
        acc = MFMA(al, bh, acc);
        acc = MFMA(ah, bl, acc);
        acc = MFMA(al, bl, acc);
    }
    #pragma unroll
    for (int r = 0; r < 4; ++r)
        qt[(row0 + kgrp * 4 + r) * 512 + col0 + frow] = acc[r];
}

// ---- final MLP: 1280 rows, one wave per row ----
__global__ __launch_bounds__(256) void dense_out(const float* __restrict__ qt,
        const unsigned* __restrict__ hpk,
        const float* __restrict__ W1, const float* __restrict__ b1,
        const float* __restrict__ W2, const float* __restrict__ b2, float* __restrict__ out)
{
    const int r    = blockIdx.x * 4 + (threadIdx.x >> 6);
    const int lane = threadIdx.x & 63;
    int qi, ri;
    if (r < 256) { qi = r; ri = r; }
    else { const int g = (r - 256) >> 8; const int b = (r - 256) & 255; qi = b; ri = (b + g + 1) & 255; }

    float p[10];
    #pragma unroll
    for (int u = 0; u < 10; ++u) p[u] = 0.0f;
    for (int k = lane; k < 512; k += 64) {
        const float xq = qt[qi * 512 + k];
        #pragma unroll
        for (int u = 0; u < 10; ++u) p[u] += xq * W1[k * 10 + u];
    }
    for (int k = lane; k < 512; k += 64) {
        const unsigned v = hpk[(256 + ri) * 512 + k];
        const float xr = bf2f((u16)v) + bf2f((u16)(v >> 16));
        #pragma unroll
        for (int u = 0; u < 10; ++u) p[u] += xr * W1[(512 + k) * 10 + u];
    }
    #pragma unroll
    for (int off = 32; off; off >>= 1) {
        #pragma unroll
        for (int u = 0; u < 10; ++u) p[u] += __shfl_xor(p[u], off);
    }
    float s = b2[0];
    #pragma unroll
    for (int u = 0; u < 10; ++u) {
        const float h1 = fmaxf(p[u] + b1[u], 0.0f);
        s += h1 * W2[u];
    }
    if (lane == 0) out[r] = fmaxf(s, 0.0f);
}

extern "C" void kernel_launch(void* const* d_in, const int* in_sizes, int n_in,
                              void* d_out, int out_size, void* d_ws, size_t ws_size,
                              hipStream_t stream)
{
    const float* emb  = (const float*)d_in[0];
    const float* Wk   = (const float*)d_in[1];
    const float* bias = (const float*)d_in[2];
    const float* wi   = (const float*)d_in[3];
    const float* wf   = (const float*)d_in[4];
    const float* wo   = (const float*)d_in[5];
    const float* M    = (const float*)d_in[6];
    const float* W1   = (const float*)d_in[7];
    const float* b1   = (const float*)d_in[8];
    const float* W2   = (const float*)d_in[9];
    const float* b2   = (const float*)d_in[10];
    const int*   qtok = (const int*)d_in[11];
    const int*   rtok = (const int*)d_in[12];
    const int*   qlen = (const int*)d_in[13];
    const int*   rlen = (const int*)d_in[14];
    float* out = (float*)d_out;

    // workspace layout (16B-aligned); total ~10.5 MB
    char* ws = (char*)d_ws;
    u16*      Wt_hi = (u16*)(ws + 0);            // 2048*768*2  = 3,145,728
    u16*      Wt_lo = (u16*)(ws + 3145728);      //               3,145,728
    u16*      Mt_hi = (u16*)(ws + 6291456);      // 512*512*2   =   524,288
    u16*      Mt_lo = (u16*)(ws + 6815744);      //                 524,288
    unsigned* h0p   = (unsigned*)(ws + 7340032); // 512*512*4   = 1,048,576 (packed lo|hi)
    unsigned* h1p   = (unsigned*)(ws + 8388608); //               1,048,576
    float*    qt    = (float*)(ws + 9437184);    //                 524,288
    unsigned* ctr   = (unsigned*)(ws + 9961472); // 8 counters @ 128B stride

    transpose_split<<<dim3(64, 24), dim3(32, 8), 0, stream>>>(Wk, Wt_hi, Wt_lo, 768, 2048);
    transpose_split<<<dim3(16, 16), dim3(32, 8), 0, stream>>>(M, Mt_hi, Mt_lo, 512, 512);
    zero_state<<<1024, 256, 0, stream>>>(h0p, ctr);

    // opt-in to 128 KiB dynamic LDS (mechanism proven in round 11)
    hipFuncSetAttribute((const void*)lstm_persist,
                        hipFuncAttributeMaxDynamicSharedMemorySize, 131072);
    lstm_persist<<<128, 512, 131072, stream>>>(emb, qtok, rtok, qlen, rlen,
                                               Wt_hi, Wt_lo, bias, wi, wf, wo,
                                               h0p, h1p, ctr);

    // 128 steps (even) => final h lives in h0p
    qt_kernel<<<dim3(8, 16), 256, 0, stream>>>(h0p, Mt_hi, Mt_lo, qt);
    dense_out<<<320, 256, 0, stream>>>(qt, h0p, W1, b1, W2, b2, out);
}

// Round 13
// 2971.859 us; speedup vs baseline: 1.9003x; 1.9003x over previous
//
#include <hip/hip_runtime.h>

// DualEncoderLSTMDense: dual peephole-LSTM encoders (shared weights) + M-projection + tiny MLP.
// B=256, L=128, E=256, H=512, VOCAB=90000, NUM_NEG=4, forget_bias=2.0.
//
// Round 13: EXACT R8 geometry (the only config that keeps streamed W L2-resident:
// 256 blocks x 256 threads, 64KB static LDS, group = 32 blocks) with two sync changes:
//  (1) poll = pure RELAXED atomic LOADS (R7's RMW-poll serializes ~32 RMWs on one line
//      at the coherence point every step = up to ~9us/step; loads are fresh at MALL and
//      don't serialize). h data path already proves agent relaxed loads are fresh.
//  (2) wave-autonomous barrier: each WAVE publishes +1 after its own vmcnt(0) drain;
//      wait target = 128*t (32 blocks x 4 waves). No __syncthreads in the loop.
// Numerics bit-identical to R8/R9 (absmax 1.953125e-3).

typedef unsigned short u16;
typedef unsigned long long u64;
typedef __attribute__((ext_vector_type(8))) short    s16x8;   // 8 bf16 = one MFMA A/B fragment
typedef __attribute__((ext_vector_type(4))) float    f32x4;
typedef __attribute__((ext_vector_type(4))) unsigned u32x4;

#define MFMA(a, b, c) __builtin_amdgcn_mfma_f32_16x16x32_bf16((a), (b), (c), 0, 0, 0)

__device__ __forceinline__ u16 f2bf(float f) {   // RNE float -> bf16
    union { float f; unsigned u; } v; v.f = f;
    unsigned r = v.u + 0x7FFFu + ((v.u >> 16) & 1u);
    return (u16)(r >> 16);
}
__device__ __forceinline__ float bf2f(u16 h) {
    union { unsigned u; float f; } v; v.u = ((unsigned)h) << 16;
    return v.f;
}
__device__ __forceinline__ float sigm(float x) { return 1.0f / (1.0f + expf(-x)); }

// ---- transpose fp32 [R][C] -> bf16 hi/lo planes [C][R] (R,C multiples of 32) ----
__global__ __launch_bounds__(256) void transpose_split(const float* __restrict__ src,
        u16* __restrict__ dhi, u16* __restrict__ dlo, int R, int C)
{
    __shared__ float tile[32][33];
    const int bx = blockIdx.x * 32;   // src col base
    const int by = blockIdx.y * 32;   // src row base
    for (int i = threadIdx.y; i < 32; i += 8)
        tile[i][threadIdx.x] = src[(size_t)(by + i) * C + bx + threadIdx.x];
    __syncthreads();
    for (int i = threadIdx.y; i < 32; i += 8) {
        float v = tile[threadIdx.x][i];
        u16 hi = f2bf(v);
        size_t o = (size_t)(bx + i) * R + by + threadIdx.x;
        dhi[o] = hi;
        dlo[o] = f2bf(v - bf2f(hi));
    }
}

// ---- zero h0 packed plane + barrier counters ----
__global__ __launch_bounds__(256) void zero_state(unsigned* __restrict__ h0p,
        unsigned* __restrict__ ctr)
{
    const int i = blockIdx.x * 256 + threadIdx.x;   // grid 1024*256 = 262144
    h0p[i] = 0;
    if (i < 8) ctr[i * 32] = 0;
}

// ---- persistent LSTM: all 128 steps, both encoders (512 batch rows) ----
// 256 blocks (1/CU): rowTile = bid&7 (64 batch rows), hidTile = bid>>3 (16 hid cols).
__global__ __launch_bounds__(256, 1) void lstm_persist(
        const float* __restrict__ emb, const int* __restrict__ qtok, const int* __restrict__ rtok,
        const int* __restrict__ qlen, const int* __restrict__ rlen,
        const u16* __restrict__ Wt_hi, const u16* __restrict__ Wt_lo,   // [2048][768]
        const float* __restrict__ bias, const float* __restrict__ wi,
        const float* __restrict__ wf, const float* __restrict__ wo,
        unsigned* __restrict__ h0p, unsigned* __restrict__ h1p,         // packed h planes
        unsigned* __restrict__ ctr)
{
    __shared__ u16 whi_h[32768];   // 64 KiB: W_hi rows [4g*16c] x K 256..767, XOR-swizzled

    const int tid = threadIdx.x, lane = tid & 63, w = tid >> 6;
    const int bid = blockIdx.x;
    const int rowTile = bid & 7, hidTile = bid >> 3;
    const int row0 = rowTile * 64 + w * 16, hid0 = hidTile * 16;
    const int frow = lane & 15, kgrp = lane >> 4;
    const int sw = (frow & 7) << 4;                // LDS XOR swizzle for this lane

    // ---- stage h-part W_hi into LDS (once): 64 rows x 64 chunks of 16B ----
    for (int i = tid; i < 4096; i += 256) {
        const int gc = i >> 6, c16 = i & 63;       // W row, 16B chunk within K-slice
        const int g = gc >> 4, cc = gc & 15;
        const s16x8 v = *(const s16x8*)(Wt_hi + (size_t)(g * 512 + hid0 + cc) * 768 + 256 + c16 * 8);
        *(s16x8*)((char*)whi_h + ((gc * 1024 + c16 * 16) ^ ((gc & 7) << 4))) = v;
    }

    // ---- per-thread constants ----
    const int   ohid = hid0 + frow;
    const float bi  = bias[ohid];
    const float bj  = bias[512 + ohid];
    const float bff = bias[1024 + ohid];
    const float bo  = bias[1536 + ohid];
    const float wiv = wi[ohid], wfv = wf[ohid], wov = wo[ohid];
    const int   arow = row0 + frow;                                 // A-fragment row
    const int*  tokp = (arow < 256) ? (qtok + arow * 128) : (rtok + (arow - 256) * 128);
    const u16*  whi_base[4];
    const u16*  wlo_base[4];
    #pragma unroll
    for (int g = 0; g < 4; ++g) {
        whi_base[g] = Wt_hi + (size_t)(g * 512 + hid0 + frow) * 768;
        wlo_base[g] = Wt_lo + (size_t)(g * 512 + hid0 + frow) * 768;
    }
    int lenv[4];
    #pragma unroll
    for (int r = 0; r < 4; ++r) {
        const int rr = row0 + kgrp * 4 + r;
        lenv[r] = (rr < 256) ? qlen[rr] : rlen[rr - 256];
    }
    float c_reg[4] = {0, 0, 0, 0}, h_reg[4] = {0, 0, 0, 0};

    __syncthreads();   // LDS W staged (once, before the loop)

    unsigned* myctr = ctr + rowTile * 32;

    for (int t = 0; t < 128; ++t) {
        const unsigned* rd = (t & 1) ? h1p : h0p;
        unsigned*       wr = (t & 1) ? h0p : h1p;

        // ---- x-part FIRST (depends only on tokens; overlaps barrier stragglers) ----
        const int    tok  = tokp[t];
        const float* xrow = emb + (size_t)tok * 256 + kgrp * 8;
        f32x4 fv[16];
        #pragma unroll
        for (int i = 0; i < 16; ++i)
            fv[i] = *(const f32x4*)(xrow + (i >> 1) * 32 + (i & 1) * 4);

        f32x4 acc[4] = {{0,0,0,0},{0,0,0,0},{0,0,0,0},{0,0,0,0}};  // gates i,j,f,o

        // x-part, K 0..255: split fp32 gather into 2 planes; bh/bl streamed; 3 products
        #pragma unroll
        for (int ks = 0; ks < 8; ++ks) {
            const f32x4 v0 = fv[2 * ks], v1 = fv[2 * ks + 1];
            const float vv[8] = {v0[0], v0[1], v0[2], v0[3], v1[0], v1[1], v1[2], v1[3]};
            s16x8 xh, xl;
            #pragma unroll
            for (int e = 0; e < 8; ++e) {
                const u16 hb = f2bf(vv[e]);
                xh[e] = (short)hb;
                xl[e] = (short)f2bf(vv[e] - bf2f(hb));
            }
            const int kk = ks * 32 + kgrp * 8;
            #pragma unroll
            for (int g = 0; g < 4; ++g) {
                const s16x8 bh = *(const s16x8*)(whi_base[g] + kk);
                const s16x8 bl = *(const s16x8*)(wlo_base[g] + kk);
                acc[g] = MFMA(xh, bh, acc[g]);
                acc[g] = MFMA(xl, bh, acc[g]);
                acc[g] = MFMA(xh, bl, acc[g]);
            }
        }

        // ---- wave-autonomous wait: 128 publishes (32 blocks x 4 waves) per step ----
        // Pure relaxed atomic LOADS: fresh at the coherence point, no RMW serialization.
        if (lane == 0) {
            const unsigned target = 128u * (unsigned)t;
            while (__hip_atomic_load(myctr, __ATOMIC_RELAXED, __HIP_MEMORY_SCOPE_AGENT) < target)
                __builtin_amdgcn_s_sleep(2);
        }
        asm volatile("" ::: "memory");   // compiler fence: keep h loads below the poll

        const unsigned* hrd = rd + arow * 512 + kgrp * 8;

        // h-part, K 256..767: A from packed-h agent atomics (fresh at MALL); bh LDS, bl streamed
        #pragma unroll 2
        for (int ks = 0; ks < 16; ++ks) {
            const int kh = ks * 32;
            s16x8 ah, al;
            #pragma unroll
            for (int i = 0; i < 4; ++i) {
                const u64 v = __hip_atomic_load((const u64*)(hrd + kh + 2 * i),
                                                __ATOMIC_RELAXED, __HIP_MEMORY_SCOPE_AGENT);
                const unsigned w0 = (unsigned)v, w1 = (unsigned)(v >> 32);
                ah[2 * i]     = (short)(u16)w0;
                al[2 * i]     = (short)(u16)(w0 >> 16);
                ah[2 * i + 1] = (short)(u16)w1;
                al[2 * i + 1] = (short)(u16)(w1 >> 16);
            }
            #pragma unroll
            for (int g = 0; g < 4; ++g) {
                const int gr = g * 16 + frow;
                const s16x8 bh = *(const s16x8*)((const char*)whi_h + ((gr * 1024 + (kh + kgrp * 8) * 2) ^ sw));
                const s16x8 bl = *(const s16x8*)(wlo_base[g] + 256 + kh + kgrp * 8);
                acc[g] = MFMA(ah, bh, acc[g]);
                acc[g] = MFMA(al, bh, acc[g]);
                acc[g] = MFMA(ah, bl, acc[g]);
                acc[g] = MFMA(al, bl, acc[g]);
            }
        }

        // gates + peepholes + masking (state in registers); publish h packed via sc1 store
        #pragma unroll
        for (int r = 0; r < 4; ++r) {
            const float cold = c_reg[r];
            const float ig = sigm(acc[0][r] + bi + wiv * cold);
            const float jg = tanhf(acc[1][r] + bj);
            const float fg = sigm(acc[2][r] + bff + wfv * cold + 2.0f);
            const float cn = fg * cold + ig * jg;
            const float og = sigm(acc[3][r] + bo + wov * cn);
            const float hn = og * tanhf(cn);
            const bool upd = (t < lenv[r]);
            c_reg[r] = upd ? cn : c_reg[r];
            h_reg[r] = upd ? hn : h_reg[r];
            const int off = (row0 + kgrp * 4 + r) * 512 + ohid;
            const u16 hb = f2bf(h_reg[r]);
            const u16 lb = f2bf(h_reg[r] - bf2f(hb));
            __hip_atomic_store(wr + off, ((unsigned)lb << 16) | (unsigned)hb,
                               __ATOMIC_RELAXED, __HIP_MEMORY_SCOPE_AGENT);
        }

        // ---- per-wave publish: drain this wave's stores, then one relaxed add ----
        asm volatile("s_waitcnt vmcnt(0)" ::: "memory");
        if (lane == 0)
            __hip_atomic_fetch_add(myctr, 1u, __ATOMIC_RELAXED, __HIP_MEMORY_SCOPE_AGENT);
        asm volatile("" ::: "memory");
    }
}

// ---- qt[256][512] = q_h @ M (MFMA, h from packed plane, M hi+lo, 4 products) ----
// grid (8,16), 4 waves 2x2
__global__ __launch_bounds__(256) void qt_kernel(
        const unsigned* __restrict__ hpk,
        const u16* __restrict__ Mt_hi, const u16* __restrict__ Mt_lo, float* __restrict__ qt)
{
    const int tid = threadIdx.x, lane = tid & 63, w = tid >> 6;
    const int wr = w >> 1, wc = w & 1;
    const int row0 = blockIdx.x * 32 + wr * 16;
    const int col0 = blockIdx.y * 32 + wc * 16;
    const int frow = lane & 15, kgrp = lane >> 4;
    f32x4 acc = {0, 0, 0, 0};
    const unsigned* ap = hpk + (row0 + frow) * 512 + kgrp * 8;
    const u16* bph = Mt_hi + (col0 + frow) * 512 + kgrp * 8;
    const u16* bpl = Mt_lo + (col0 + frow) * 512 + kgrp * 8;
    #pragma unroll 4
    for (int ks = 0; ks < 16; ++ks) {
        const u32x4 a0 = *(const u32x4*)(ap + ks * 32);
        const u32x4 a1 = *(const u32x4*)(ap + ks * 32 + 4);
        s16x8 ah, al;
        #pragma unroll
        for (int i = 0; i < 4; ++i) {
            ah[i]     = (short)(u16)a0[i];
            al[i]     = (short)(u16)(a0[i] >> 16);
            ah[4 + i] = (short)(u16)a1[i];
            al[4 + i] = (short)(u16)(a1[i] >> 16);
        }
        const s16x8 bh = *(const s16x8*)(bph + ks * 32);
        const s16x8 bl = *(const s16x8*)(bpl + ks * 32);
        acc = MFMA(ah, bh, acc);
        acc = MFMA(al, bh, acc);
        acc = MFMA(ah, bl, acc);
        acc = MFMA(al, bl, acc);
    }
    #pragma unroll
    for (int r = 0; r < 4; ++r)
        qt[(row0 + kgrp * 4 + r) * 512 + col0 + frow] = acc[r];
}

// ---- final MLP: 1280 rows, one wave per row ----
__global__ __launch_bounds__(256) void dense_out(const float* __restrict__ qt,
        const unsigned* __restrict__ hpk,
        const float* __restrict__ W1, const float* __restrict__ b1,
        const float* __restrict__ W2, const float* __restrict__ b2, float* __restrict__ out)
{
    const int r    = blockIdx.x * 4 + (threadIdx.x >> 6);
    const int lane = threadIdx.x & 63;
    int qi, ri;
    if (r < 256) { qi = r; ri = r; }
    else { const int g = (r - 256) >> 8; const int b = (r - 256) & 255; qi = b; ri = (b + g + 1) & 255; }

    float p[10];
    #pragma unroll
    for (int u = 0; u < 10; ++u) p[u] = 0.0f;
    for (int k = lane; k < 512; k += 64) {
        const float xq = qt[qi * 512 + k];
        #pragma unroll
        for (int u = 0; u < 10; ++u) p[u] += xq * W1[k * 10 + u];
    }
    for (int k = lane; k < 512; k += 64) {
        const unsigned v = hpk[(256 + ri) * 512 + k];
        const float xr = bf2f((u16)v) + bf2f((u16)(v >> 16));
        #pragma unroll
        for (int u = 0; u < 10; ++u) p[u] += xr * W1[(512 + k) * 10 + u];
    }
    #pragma unroll
    for (int off = 32; off; off >>= 1) {
        #pragma unroll
        for (int u = 0; u < 10; ++u) p[u] += __shfl_xor(p[u], off);
    }
    float s = b2[0];
    #pragma unroll
    for (int u = 0; u < 10; ++u) {
        const float h1 = fmaxf(p[u] + b1[u], 0.0f);
        s += h1 * W2[u];
    }
    if (lane == 0) out[r] = fmaxf(s, 0.0f);
}

extern "C" void kernel_launch(void* const* d_in, const int* in_sizes, int n_in,
                              void* d_out, int out_size, void* d_ws, size_t ws_size,
                              hipStream_t stream)
{
    const float* emb  = (const float*)d_in[0];
    const float* Wk   = (const float*)d_in[1];
    const float* bias = (const float*)d_in[2];
    const float* wi   = (const float*)d_in[3];
    const float* wf   = (const float*)d_in[4];
    const float* wo   = (const float*)d_in[5];
    const float* M    = (const float*)d_in[6];
    const float* W1   = (const float*)d_in[7];
    const float* b1   = (const float*)d_in[8];
    const float* W2   = (const float*)d_in[9];
    const float* b2   = (const float*)d_in[10];
    const int*   qtok = (const int*)d_in[11];
    const int*   rtok = (const int*)d_in[12];
    const int*   qlen = (const int*)d_in[13];
    const int*   rlen = (const int*)d_in[14];
    float* out = (float*)d_out;

    // workspace layout (16B-aligned); total ~10.5 MB
    char* ws = (char*)d_ws;
    u16*      Wt_hi = (u16*)(ws + 0);            // 2048*768*2  = 3,145,728
    u16*      Wt_lo = (u16*)(ws + 3145728);      //               3,145,728
    u16*      Mt_hi = (u16*)(ws + 6291456);      // 512*512*2   =   524,288
    u16*      Mt_lo = (u16*)(ws + 6815744);      //                 524,288
    unsigned* h0p   = (unsigned*)(ws + 7340032); // 512*512*4   = 1,048,576 (packed lo|hi)
    unsigned* h1p   = (unsigned*)(ws + 8388608); //               1,048,576
    float*    qt    = (float*)(ws + 9437184);    //                 524,288
    unsigned* ctr   = (unsigned*)(ws + 9961472); // 8 counters @ 128B stride

    transpose_split<<<dim3(64, 24), dim3(32, 8), 0, stream>>>(Wk, Wt_hi, Wt_lo, 768, 2048);
    transpose_split<<<dim3(16, 16), dim3(32, 8), 0, stream>>>(M, Mt_hi, Mt_lo, 512, 512);
    zero_state<<<1024, 256, 0, stream>>>(h0p, ctr);

    lstm_persist<<<256, 256, 0, stream>>>(emb, qtok, rtok, qlen, rlen,
                                          Wt_hi, Wt_lo, bias, wi, wf, wo,
                                          h0p, h1p, ctr);

    // 128 steps (even) => final h lives in h0p
    qt_kernel<<<dim3(8, 16), 256, 0, stream>>>(h0p, Mt_hi, Mt_lo, qt);
    dense_out<<<320, 256, 0, stream>>>(qt, h0p, W1, b1, W2, b2, out);
}